// Round 7
// baseline (145.067 us; speedup 1.0000x reference)
//
#include <hip/hip_runtime.h>
#include <float.h>

// Problem constants (fixed by the reference): B=2, N=M=8192, G=256
#define B_ 2
#define N_ 8192
#define G_ 256
// CELL = abs(2*(-35)/256) = 70/256 = 0.2734375 exactly representable in fp32
constexpr float X_MIN_F = -35.0f;
constexpr float CELL_F  = 0.2734375f;

using u64 = unsigned long long;
typedef float v2f __attribute__((ext_vector_type(2)));

// Workspace layout (bytes):
//   grid   i32[B*G*G]   [0, 524288)      packed (n<<1)|label, -1 invalid
//   accum  16B          [524288, 524304) {f32 sum, i32 cnt, u32 ticket, pad}
//   px     u64[CC][B*N] [524352, ...)    per-chunk packed (distbits<<32)|idx
//   py     f32[CC][B*N] after px         per-chunk min dist (y-direction)
#define OFF_ACCUM 524288
#define OFF_PX    524352

// |x| as max(x,-x): exact, folds the neg into a VOP3P source modifier so the
// packed form is a single v_pk_max_f32 (v_and has no packed variant).
__device__ __forceinline__ v2f vabs2(v2f x) {
    return __builtin_elementwise_max(x, -x);
}

// ---------------------------------------------------------------------------
// 1-NN (L1), split-K over CC column chunks, NO atomics: each block writes its
// chunk-local best to px/py with plain coalesced stores. Grid=-1 init and
// accum zeroing folded in (consumed only after the kernel boundary).
//   grid: (4, CC, 4); z = dir*2 + b. 8 rows/thread (2048 rows/block) halves
//   LDS traffic per pair vs 4 rows; distances computed 2 columns at a time in
//   packed fp32 (v_pk_add/max/min) — bit-identical IEEE per lane-half.
//   dir 0: p_i vs p_j WITH argmin — group-min over 8 columns, then an LDS
//     rescan of the winning group recovers the exact column. First-occurrence:
//     strict < at group level keeps earliest group; descending equality rescan
//     keeps smallest k; packed-u64 min across chunks keeps smallest idx.
//   dir 1: p_j vs p_i, min-dist only (reference discards that argmin).
// ---------------------------------------------------------------------------
template<int CC>
__global__ __launch_bounds__(256) void nn_kernel(const float* __restrict__ p_i,
                                                 const float* __restrict__ p_j,
                                                 u64* __restrict__ px,
                                                 float* __restrict__ py,
                                                 int* __restrict__ grid,
                                                 unsigned* __restrict__ accum)
{
    constexpr int COLS = N_ / CC;
    constexpr int NB   = 16 * CC;                // total blocks
    const int dir  = blockIdx.z >> 1;
    const int b    = blockIdx.z & 1;
    const int tid  = threadIdx.x;
    const int row0 = blockIdx.x * 2048 + tid * 8;
    const int c0   = blockIdx.y * COLS;

    const float* __restrict__ P = dir ? p_j : p_i;
    const float* __restrict__ Q = dir ? p_i : p_j;

    __shared__ __align__(16) float q[COLS * 3];
    for (int t = tid; t < COLS * 3 / 4; t += 256)
        ((float4*)q)[t] = ((const float4*)(Q + ((size_t)b * N_ + c0) * 3))[t];

    // folded init: grid = -1 (512 KB spread over all blocks), accum = 0
    {
        const int lin = blockIdx.x + 4 * (blockIdx.y + CC * blockIdx.z);
        constexpr int PER = 32768 / NB;          // uint4 per block
        for (int t = tid; t < PER; t += 256)
            ((uint4*)grid)[lin * PER + t] = make_uint4(~0u, ~0u, ~0u, ~0u);
        if (lin == 0 && tid < 4) accum[tid] = 0u;
    }

    // 8 consecutive rows = 24 consecutive floats = 6 float4
    float px_[8], py_[8], pz_[8];
    {
        const float4* pp = (const float4*)(P + ((size_t)b * N_ + row0) * 3);
        float4 v0 = pp[0], v1 = pp[1], v2 = pp[2];
        float4 v3 = pp[3], v4 = pp[4], v5 = pp[5];
        float X[8] = {v0.x, v0.w, v1.z, v2.y, v3.x, v3.w, v4.z, v5.y};
        float Y[8] = {v0.y, v1.x, v1.w, v2.z, v3.y, v4.x, v4.w, v5.z};
        float Z[8] = {v0.z, v1.y, v2.x, v2.w, v3.z, v4.y, v5.x, v5.w};
#pragma unroll
        for (int r = 0; r < 8; r++) { px_[r] = X[r]; py_[r] = Y[r]; pz_[r] = Z[r]; }
    }

    __syncthreads();

    if (dir == 0) {
        float best[8]; int gcol[8];
#pragma unroll
        for (int r = 0; r < 8; r++) { best[r] = FLT_MAX; gcol[r] = 0; }

        for (int jg = 0; jg < COLS; jg += 8) {
            const float4* qv = (const float4*)&q[jg * 3];
            float4 v0 = qv[0], v1 = qv[1], v2 = qv[2];
            float4 v3 = qv[3], v4 = qv[4], v5 = qv[5];
            v2f qx2[4] = {{v0.x, v0.w}, {v1.z, v2.y}, {v3.x, v3.w}, {v4.z, v5.y}};
            v2f qy2[4] = {{v0.y, v1.x}, {v1.w, v2.z}, {v3.y, v4.x}, {v4.w, v5.z}};
            v2f qz2[4] = {{v0.z, v1.y}, {v2.x, v2.w}, {v3.z, v4.y}, {v5.x, v5.w}};
#pragma unroll
            for (int r = 0; r < 8; r++) {
                v2f P2x = {px_[r], px_[r]};
                v2f P2y = {py_[r], py_[r]};
                v2f P2z = {pz_[r], pz_[r]};
                v2f s[4];
#pragma unroll
                for (int t = 0; t < 4; t++) {
                    // bit-match reference: (|d0| + |d1|) + |d2|, left-assoc
                    s[t] = (vabs2(P2x - qx2[t]) + vabs2(P2y - qy2[t]))
                           + vabs2(P2z - qz2[t]);
                }
                v2f m2 = __builtin_elementwise_min(
                             __builtin_elementwise_min(s[0], s[1]),
                             __builtin_elementwise_min(s[2], s[3]));
                float m = fminf(m2.x, m2.y);     // exact, order-independent
                bool lt = m < best[r];           // strict < -> earliest group
                best[r] = lt ? m : best[r];
                gcol[r] = lt ? jg : gcol[r];
            }
        }
        // rescan winning group: recompute identical IEEE expressions,
        // descending equality overwrite -> smallest k = first occurrence.
        const size_t o = (size_t)blockIdx.y * (B_ * N_) + b * N_ + row0;
#pragma unroll
        for (int r = 0; r < 8; r++) {
            const float4* qv = (const float4*)&q[gcol[r] * 3];
            float4 v0 = qv[0], v1 = qv[1], v2 = qv[2];
            float4 v3 = qv[3], v4 = qv[4], v5 = qv[5];
            float qx[8] = {v0.x, v0.w, v1.z, v2.y, v3.x, v3.w, v4.z, v5.y};
            float qy[8] = {v0.y, v1.x, v1.w, v2.z, v3.y, v4.x, v4.w, v5.z};
            float qz[8] = {v0.z, v1.y, v2.x, v2.w, v3.z, v4.y, v5.x, v5.w};
            int kk = 0;
#pragma unroll
            for (int k = 7; k >= 0; k--) {
                float d = (fabsf(px_[r] - qx[k]) + fabsf(py_[r] - qy[k]))
                          + fabsf(pz_[r] - qz[k]);
                kk = (d == best[r]) ? k : kk;
            }
            int bidx = c0 + gcol[r] + kk;
            // non-negative fp32 bits order like unsigned; idx in low bits ->
            // u64 min over chunks keeps (min dist, then min idx) = first occ.
            px[o + r] = ((u64)__float_as_uint(best[r]) << 32) | (unsigned)bidx;
        }
    } else {
        v2f bm[8];
#pragma unroll
        for (int r = 0; r < 8; r++) bm[r] = (v2f){FLT_MAX, FLT_MAX};

        for (int jg = 0; jg < COLS; jg += 8) {
            const float4* qv = (const float4*)&q[jg * 3];
            float4 v0 = qv[0], v1 = qv[1], v2 = qv[2];
            float4 v3 = qv[3], v4 = qv[4], v5 = qv[5];
            v2f qx2[4] = {{v0.x, v0.w}, {v1.z, v2.y}, {v3.x, v3.w}, {v4.z, v5.y}};
            v2f qy2[4] = {{v0.y, v1.x}, {v1.w, v2.z}, {v3.y, v4.x}, {v4.w, v5.z}};
            v2f qz2[4] = {{v0.z, v1.y}, {v2.x, v2.w}, {v3.z, v4.y}, {v5.x, v5.w}};
#pragma unroll
            for (int r = 0; r < 8; r++) {
                v2f P2x = {px_[r], px_[r]};
                v2f P2y = {py_[r], py_[r]};
                v2f P2z = {pz_[r], pz_[r]};
#pragma unroll
                for (int t = 0; t < 4; t++) {
                    v2f s = (vabs2(P2x - qx2[t]) + vabs2(P2y - qy2[t]))
                            + vabs2(P2z - qz2[t]);
                    bm[r] = __builtin_elementwise_min(bm[r], s);
                }
            }
        }
        const size_t o = (size_t)blockIdx.y * (B_ * N_) + b * N_ + row0;
#pragma unroll
        for (int r = 0; r < 8; r++) py[o + r] = fminf(bm[r].x, bm[r].y);
    }
}

// ---------------------------------------------------------------------------
// Cross-chunk reduce + label + scatter. 1024 blocks x 256 threads: 16 threads
// per point (LDS atomicMin combine), 16 points per block -> 256K threads keep
// the 1M cross-XCD partial-loads latency-hidden.
// Last-write-wins in point order n == max n wins -> atomicMax on packed
// (n<<1 | label); grid initialized to -1 by nn_kernel.
// ---------------------------------------------------------------------------
template<int CC>
__global__ __launch_bounds__(256) void reduce_scatter_kernel(
    const u64* __restrict__ px, const float* __restrict__ py,
    const float* __restrict__ flow, const int* __restrict__ nflow,
    const float* __restrict__ Pj, int* __restrict__ grid)
{
    __shared__ u64      sbx[16];
    __shared__ unsigned sby[16];
    const int tid = threadIdx.x;
    const int p   = tid & 15;                    // point within block
    const int g   = tid >> 4;                    // chunk group 0..15
    constexpr int CPG = CC / 16;                 // chunks per group

    if (tid < 16) { sbx[tid] = ~0ull; sby[tid] = ~0u; }
    __syncthreads();

    const int pt = blockIdx.x * 16 + p;          // in [0, B*N)
    u64   bx = ~0ull;
    float by = FLT_MAX;
#pragma unroll
    for (int k = 0; k < CPG; k++) {
        int c = g * CPG + k;
        u64 v = px[(size_t)c * (B_ * N_) + pt];
        bx = v < bx ? v : bx;
        by = fminf(by, py[(size_t)c * (B_ * N_) + pt]);
    }
    atomicMin(&sbx[p], bx);
    atomicMin(&sby[p], __float_as_uint(by));
    __syncthreads();

    if (tid < 16) {
        u64 fx = sbx[tid];
        float dx = __uint_as_float((unsigned)(fx >> 32));
        float dy = __uint_as_float(sby[tid]);
        float rigid = (dx + dy) * 0.5f;

        const int i = blockIdx.x * 16 + tid;
        const int b = i >> 13;                   // N = 8192
        const int n = i & (N_ - 1);

        bool dyn  = flow[i] > rigid;
        int label = dyn ? 1 : 0;
        int idx   = dyn ? nflow[i] : (int)(unsigned)(fx & 0xFFFFFFFFull);

        const float* qp = Pj + ((size_t)b * N_ + idx) * 3;
        float xx = qp[0], yy = qp[1];

        // bit-match ref: (p - shift) / CELL, IEEE fp32 divide, trunc cast
        int cx = (int)((xx - X_MIN_F) / CELL_F);
        int cy = (int)((yy - X_MIN_F) / CELL_F);

        atomicMax(&grid[(b << 16) + cx * G_ + cy], (n << 1) | label);
    }
}

// ---------------------------------------------------------------------------
// Cross-entropy over valid grid cells + fused finalize: last block (ticket)
// reads the device-scope accumulators and writes the loss.
// ---------------------------------------------------------------------------
__global__ __launch_bounds__(256) void ce_kernel(const float* __restrict__ mos,
                                                 const int* __restrict__ grid,
                                                 float* __restrict__ accum,
                                                 float* __restrict__ out)
{
    int i = blockIdx.x * 256 + threadIdx.x;      // i in [0, B*G*G) = 131072
    float lsum = 0.0f;
    int   lcnt = 0;

    int packed = grid[i];
    if (packed >= 0) {
        int b    = i >> 16;                      // G*G = 65536
        int cell = i & 0xFFFF;
        float m0 = mos[((size_t)b * 2 + 0) * 65536 + cell];
        float m1 = mos[((size_t)b * 2 + 1) * 65536 + cell];
        float mx = fmaxf(m0, m1);
        float lse = logf(expf(m0 - mx) + expf(m1 - mx));
        float sh  = ((packed & 1) ? m1 : m0) - mx;   // stable log_softmax
        lsum = sh - lse;
        lcnt = 1;
    }

    // wave-64 shuffle reduction
#pragma unroll
    for (int o = 32; o > 0; o >>= 1) {
        lsum += __shfl_down(lsum, o);
        lcnt += __shfl_down(lcnt, o);
    }
    __shared__ float wsum[4];
    __shared__ int   wcnt[4];
    int wave = threadIdx.x >> 6;
    if ((threadIdx.x & 63) == 0) { wsum[wave] = lsum; wcnt[wave] = lcnt; }
    __syncthreads();
    if (threadIdx.x == 0) {
        float s = wsum[0] + wsum[1] + wsum[2] + wsum[3];
        int   c = wcnt[0] + wcnt[1] + wcnt[2] + wcnt[3];
        atomicAdd(&accum[0], s);
        atomicAdd((int*)&accum[1], c);
        __threadfence();
        unsigned t = atomicAdd((unsigned*)&accum[2], 1u);
        if (t == gridDim.x - 1) {
            float S = atomicAdd(&accum[0], 0.0f);
            int   C = atomicAdd((int*)&accum[1], 0);
            out[0] = -S / (float)(C > 0 ? C : 1);
        }
    }
}

// ---------------------------------------------------------------------------
template<int CC>
static void run(const float* p_i, const float* mos, const float* p_j,
                const float* flow, const int* nflow, float* out,
                char* ws, hipStream_t stream)
{
    int*   grid  = (int*)ws;
    float* accum = (float*)(ws + OFF_ACCUM);
    u64*   px    = (u64*)(ws + OFF_PX);
    float* py    = (float*)(ws + OFF_PX + (size_t)CC * B_ * N_ * 8);

    dim3 g(4, CC, 4);
    nn_kernel<CC><<<g, 256, 0, stream>>>(p_i, p_j, px, py, (int*)grid,
                                         (unsigned*)accum);
    reduce_scatter_kernel<CC><<<(B_ * N_) / 16, 256, 0, stream>>>(
        px, py, flow, nflow, p_j, grid);
    ce_kernel<<<(B_ * G_ * G_) / 256, 256, 0, stream>>>(mos, grid, accum, out);
}

extern "C" void kernel_launch(void* const* d_in, const int* in_sizes, int n_in,
                              void* d_out, int out_size, void* d_ws, size_t ws_size,
                              hipStream_t stream)
{
    const float* p_i   = (const float*)d_in[0];   // (B,N,3)
    const float* mos   = (const float*)d_in[1];   // (B,2,G,G)
    const float* p_j   = (const float*)d_in[2];   // (B,M,3)
    const float* flow  = (const float*)d_in[3];   // (B,N)
    const int*   nflow = (const int*)d_in[4];     // (B,N,1)
    float* out = (float*)d_out;
    char* ws = (char*)d_ws;

    // scratch: OFF_PX + CC*B*N*12 bytes. CC=64 -> ~13.1 MB, 32 -> ~6.8 MB,
    // 16 -> ~3.7 MB
    if (ws_size >= OFF_PX + (size_t)64 * B_ * N_ * 12)
        run<64>(p_i, mos, p_j, flow, nflow, out, ws, stream);
    else if (ws_size >= OFF_PX + (size_t)32 * B_ * N_ * 12)
        run<32>(p_i, mos, p_j, flow, nflow, out, ws, stream);
    else
        run<16>(p_i, mos, p_j, flow, nflow, out, ws, stream);
}

// Round 8
// 131.950 us; speedup vs baseline: 1.0994x; 1.0994x over previous
//
#include <hip/hip_runtime.h>
#include <float.h>

// Problem constants (fixed by the reference): B=2, N=M=8192, G=256
#define B_ 2
#define N_ 8192
#define G_ 256
// CELL = abs(2*(-35)/256) = 70/256 = 0.2734375 exactly representable in fp32
constexpr float X_MIN_F = -35.0f;
constexpr float CELL_F  = 0.2734375f;

using u64 = unsigned long long;

// Workspace layout (bytes):
//   chamx  u64[B*N]    [0, 131072)       packed (distbits<<32)|idx, atomicMin
//   chamy  u32[B*N]    [131072, 196608)  dist bits only, atomicMin
//   grid   i32[B*G*G]  [196608, 720896)  packed (n<<1)|label, -1 invalid
//   accum  16B         [720896, 720912)  {f32 sum, i32 cnt, u32 ticket, pad}
#define OFF_CHAMY 131072
#define OFF_GRID  196608
#define OFF_ACCUM 720896

// ---------------------------------------------------------------------------
// 1-NN (L1) over 128-column chunks, combined via global atomicMin (measured
// free in-kernel: R2's atomic nn == R6's atomic-free nn at ~44 us — and it
// deletes the 13 MB partials pipeline + reduce kernel entirely).
//   grid: (8, 64, 4); z = dir*2 + b. 4 rows/thread; columns staged in LDS
//   (tight xyz pack, float4 reads -> ds_read_b128 same-address broadcast).
//   dir 0: p_i vs p_j WITH argmin — group-min over 8 columns (min-tree:
//     1 cmp + 2 cndmask per GROUP, not per pair), then an LDS rescan of the
//     winning group recovers the exact column. First-occurrence: strict < at
//     group level keeps earliest group; descending equality rescan keeps
//     smallest k; packed-u64 atomicMin across chunks keeps smallest idx on
//     distance ties.
//   dir 1: p_j vs p_i, min-dist only (reference discards that argmin).
// Grid=-1 init + accum zeroing folded in (consumed only after the kernel
// boundary). chamx/chamy are pre-set to 0xFF by a cheap memset (atomic tgt).
// ---------------------------------------------------------------------------
__global__ __launch_bounds__(256) void nn_kernel(const float* __restrict__ p_i,
                                                 const float* __restrict__ p_j,
                                                 u64* __restrict__ chamx,
                                                 unsigned* __restrict__ chamy,
                                                 int* __restrict__ grid,
                                                 unsigned* __restrict__ accum)
{
    constexpr int COLS = 128;
    const int dir  = blockIdx.z >> 1;
    const int b    = blockIdx.z & 1;
    const int tid  = threadIdx.x;
    const int row0 = blockIdx.x * 1024 + tid * 4;
    const int c0   = blockIdx.y * COLS;

    const float* __restrict__ P = dir ? p_j : p_i;
    const float* __restrict__ Q = dir ? p_i : p_j;

    __shared__ __align__(16) float q[COLS * 3];
    if (tid < COLS * 3 / 4)
        ((float4*)q)[tid] = ((const float4*)(Q + ((size_t)b * N_ + c0) * 3))[tid];

    // folded init: grid = -1 (512 KB over 2048 blocks), accum = 0
    {
        const int lin = blockIdx.x + 8 * (blockIdx.y + 64 * blockIdx.z);
        if (tid < 16)                            // 16 uint4 per block
            ((uint4*)grid)[lin * 16 + tid] = make_uint4(~0u, ~0u, ~0u, ~0u);
        if (lin == 0 && tid < 4) accum[tid] = 0u;
    }

    // 4 consecutive rows = 12 consecutive floats = 3 float4
    const float4* pp = (const float4*)(P + ((size_t)b * N_ + row0) * 3);
    float4 r0 = pp[0], r1 = pp[1], r2 = pp[2];
    float px_[4] = {r0.x, r0.w, r1.z, r2.y};
    float py_[4] = {r0.y, r1.x, r1.w, r2.z};
    float pz_[4] = {r0.z, r1.y, r2.x, r2.w};

    float best[4];
#pragma unroll
    for (int r = 0; r < 4; r++) best[r] = FLT_MAX;

    __syncthreads();

    if (dir == 0) {
        int gcol[4] = {0, 0, 0, 0};              // winning group base (local)
        for (int jg = 0; jg < COLS; jg += 8) {
            const float4* qv = (const float4*)&q[jg * 3];
            float4 v0 = qv[0], v1 = qv[1], v2 = qv[2];
            float4 v3 = qv[3], v4 = qv[4], v5 = qv[5];
            float qx[8] = {v0.x, v0.w, v1.z, v2.y, v3.x, v3.w, v4.z, v5.y};
            float qy[8] = {v0.y, v1.x, v1.w, v2.z, v3.y, v4.x, v4.w, v5.z};
            float qz[8] = {v0.z, v1.y, v2.x, v2.w, v3.z, v4.y, v5.x, v5.w};
#pragma unroll
            for (int r = 0; r < 4; r++) {
                float d[8];
#pragma unroll
                for (int k = 0; k < 8; k++)
                    // bit-match reference: (|d0| + |d1|) + |d2|, left-assoc
                    d[k] = (fabsf(px_[r] - qx[k]) + fabsf(py_[r] - qy[k]))
                           + fabsf(pz_[r] - qz[k]);
                // min-tree (order-independent: min is assoc/comm, no NaN)
                float m01 = fminf(d[0], d[1]), m23 = fminf(d[2], d[3]);
                float m45 = fminf(d[4], d[5]), m67 = fminf(d[6], d[7]);
                float m = fminf(fminf(m01, m23), fminf(m45, m67));
                bool lt = m < best[r];           // strict < -> earliest group
                best[r] = lt ? m : best[r];
                gcol[r] = lt ? jg : gcol[r];
            }
        }
        // rescan winning group: recompute identical IEEE expressions,
        // descending equality overwrite -> smallest k = first occurrence.
#pragma unroll
        for (int r = 0; r < 4; r++) {
            const float4* qv = (const float4*)&q[gcol[r] * 3];
            float4 v0 = qv[0], v1 = qv[1], v2 = qv[2];
            float4 v3 = qv[3], v4 = qv[4], v5 = qv[5];
            float qx[8] = {v0.x, v0.w, v1.z, v2.y, v3.x, v3.w, v4.z, v5.y};
            float qy[8] = {v0.y, v1.x, v1.w, v2.z, v3.y, v4.x, v4.w, v5.z};
            float qz[8] = {v0.z, v1.y, v2.x, v2.w, v3.z, v4.y, v5.x, v5.w};
            int kk = 0;
#pragma unroll
            for (int k = 7; k >= 0; k--) {
                float d = (fabsf(px_[r] - qx[k]) + fabsf(py_[r] - qy[k]))
                          + fabsf(pz_[r] - qz[k]);
                kk = (d == best[r]) ? k : kk;
            }
            int bidx = c0 + gcol[r] + kk;
            // non-negative fp32 bits order like unsigned; idx in low bits ->
            // atomicMin keeps (min dist, then min idx) = first occurrence.
            u64 pk = ((u64)__float_as_uint(best[r]) << 32) | (unsigned)bidx;
            atomicMin(&chamx[(size_t)b * N_ + row0 + r], pk);
        }
    } else {
        for (int jg = 0; jg < COLS; jg += 8) {
            const float4* qv = (const float4*)&q[jg * 3];
            float4 v0 = qv[0], v1 = qv[1], v2 = qv[2];
            float4 v3 = qv[3], v4 = qv[4], v5 = qv[5];
            float qx[8] = {v0.x, v0.w, v1.z, v2.y, v3.x, v3.w, v4.z, v5.y};
            float qy[8] = {v0.y, v1.x, v1.w, v2.z, v3.y, v4.x, v4.w, v5.z};
            float qz[8] = {v0.z, v1.y, v2.x, v2.w, v3.z, v4.y, v5.x, v5.w};
#pragma unroll
            for (int r = 0; r < 4; r++) {
#pragma unroll
                for (int k = 0; k < 8; k++) {
                    float d = (fabsf(px_[r] - qx[k]) + fabsf(py_[r] - qy[k]))
                              + fabsf(pz_[r] - qz[k]);
                    best[r] = fminf(best[r], d);
                }
            }
        }
#pragma unroll
        for (int r = 0; r < 4; r++)
            atomicMin(&chamy[(size_t)b * N_ + row0 + r],
                      __float_as_uint(best[r]));
    }
}

// ---------------------------------------------------------------------------
// Per-point label + scatter into the (B,G,G) grid (reads only 192 KB).
// Last-write-wins in point order n == max n wins -> atomicMax on packed
// (n<<1 | label); grid initialized to -1 by nn_kernel.
// ---------------------------------------------------------------------------
__global__ __launch_bounds__(256) void scatter_kernel(
    const u64* __restrict__ chamx, const unsigned* __restrict__ chamy,
    const float* __restrict__ flow, const int* __restrict__ nflow,
    const float* __restrict__ Pj, int* __restrict__ grid)
{
    int i = blockIdx.x * 256 + threadIdx.x;      // i in [0, B*N)
    int b = i >> 13;                             // N = 8192
    int n = i & (N_ - 1);

    u64 pX = chamx[i];
    float dx = __uint_as_float((unsigned)(pX >> 32));
    float dy = __uint_as_float(chamy[i]);
    float rigid = (dx + dy) * 0.5f;

    bool dyn  = flow[i] > rigid;
    int label = dyn ? 1 : 0;
    int idx   = dyn ? nflow[i] : (int)(unsigned)(pX & 0xFFFFFFFFull);

    const float* qp = Pj + ((size_t)b * N_ + idx) * 3;
    float x = qp[0], y = qp[1];

    // bit-match reference: (p - shift) / CELL, IEEE fp32 divide, trunc cast
    int cx = (int)((x - X_MIN_F) / CELL_F);
    int cy = (int)((y - X_MIN_F) / CELL_F);

    atomicMax(&grid[(b << 16) + cx * G_ + cy], (n << 1) | label);
}

// ---------------------------------------------------------------------------
// Cross-entropy over valid grid cells + fused finalize: last block (ticket)
// reads the device-scope accumulators and writes the loss.
// ---------------------------------------------------------------------------
__global__ __launch_bounds__(256) void ce_kernel(const float* __restrict__ mos,
                                                 const int* __restrict__ grid,
                                                 float* __restrict__ accum,
                                                 float* __restrict__ out)
{
    int i = blockIdx.x * 256 + threadIdx.x;      // i in [0, B*G*G) = 131072
    float lsum = 0.0f;
    int   lcnt = 0;

    int packed = grid[i];
    if (packed >= 0) {
        int b    = i >> 16;                      // G*G = 65536
        int cell = i & 0xFFFF;
        float m0 = mos[((size_t)b * 2 + 0) * 65536 + cell];
        float m1 = mos[((size_t)b * 2 + 1) * 65536 + cell];
        float mx = fmaxf(m0, m1);
        float lse = logf(expf(m0 - mx) + expf(m1 - mx));
        float sh  = ((packed & 1) ? m1 : m0) - mx;   // stable log_softmax
        lsum = sh - lse;
        lcnt = 1;
    }

    // wave-64 shuffle reduction
#pragma unroll
    for (int o = 32; o > 0; o >>= 1) {
        lsum += __shfl_down(lsum, o);
        lcnt += __shfl_down(lcnt, o);
    }
    __shared__ float wsum[4];
    __shared__ int   wcnt[4];
    int wave = threadIdx.x >> 6;
    if ((threadIdx.x & 63) == 0) { wsum[wave] = lsum; wcnt[wave] = lcnt; }
    __syncthreads();
    if (threadIdx.x == 0) {
        float s = wsum[0] + wsum[1] + wsum[2] + wsum[3];
        int   c = wcnt[0] + wcnt[1] + wcnt[2] + wcnt[3];
        atomicAdd(&accum[0], s);
        atomicAdd((int*)&accum[1], c);
        __threadfence();
        unsigned t = atomicAdd((unsigned*)&accum[2], 1u);
        if (t == gridDim.x - 1) {
            float S = atomicAdd(&accum[0], 0.0f);
            int   C = atomicAdd((int*)&accum[1], 0);
            out[0] = -S / (float)(C > 0 ? C : 1);
        }
    }
}

// ---------------------------------------------------------------------------
extern "C" void kernel_launch(void* const* d_in, const int* in_sizes, int n_in,
                              void* d_out, int out_size, void* d_ws, size_t ws_size,
                              hipStream_t stream)
{
    const float* p_i   = (const float*)d_in[0];   // (B,N,3)
    const float* mos   = (const float*)d_in[1];   // (B,2,G,G)
    const float* p_j   = (const float*)d_in[2];   // (B,M,3)
    const float* flow  = (const float*)d_in[3];   // (B,N)
    const int*   nflow = (const int*)d_in[4];     // (B,N,1)
    float* out = (float*)d_out;
    char* ws = (char*)d_ws;

    u64*      chamx = (u64*)ws;
    unsigned* chamy = (unsigned*)(ws + OFF_CHAMY);
    int*      grid  = (int*)(ws + OFF_GRID);
    float*    accum = (float*)(ws + OFF_ACCUM);

    // 0xFF over chamx/chamy only (atomicMin identity); grid/accum init is
    // folded into nn_kernel.
    hipMemsetAsync(ws, 0xFF, OFF_GRID, stream);

    dim3 g(8, 64, 4);                             // 2048 blocks
    nn_kernel<<<g, 256, 0, stream>>>(p_i, p_j, chamx, chamy, grid,
                                     (unsigned*)accum);
    scatter_kernel<<<(B_ * N_) / 256, 256, 0, stream>>>(chamx, chamy, flow,
                                                        nflow, p_j, grid);
    ce_kernel<<<(B_ * G_ * G_) / 256, 256, 0, stream>>>(mos, grid, accum, out);
}